// Round 5
// baseline (586.011 us; speedup 1.0000x reference)
//
#include <hip/hip_runtime.h>
#include <stdint.h>

typedef unsigned short u16;
typedef unsigned int u32;

#define NV 400000
#define KOFF 27
#define KPAD 29                               // 27 real + 2 pipeline-pad slices (-1)
#define EPS_BN 1e-5f
#define NROWT 64                              // rows per wave
#define NTILE (NV / NROWT)                    // 6250 wave-tiles

#define INV_BYTES (KPAD * NV * 4)             // 46.4 MB
#define FEATSBF_OFF INV_BYTES                 // 51.2 MB
#define WT_OFF (FEATSBF_OFF + NV * 64 * 2)    // 28 tiles (27 + zero pad)
#define STATS_OFF (WT_OFF + 28 * 64 * 64 * 2)
#define CNT_OFF (STATS_OFF + 1024)

using short8 = __attribute__((ext_vector_type(8))) short;
using floatx4 = __attribute__((ext_vector_type(4))) float;

__device__ __forceinline__ u16 f2bf(float f) {
  u32 u = __float_as_uint(f);
  u += 0x7FFFu + ((u >> 16) & 1u);
  return (u16)(u >> 16);
}

// ---- prep: inv=-1 (29 slices), stats=0, feats->bf16, W->Wt (+zero pad tile) ----
__global__ void k_prep(int* __restrict__ inv, float* __restrict__ stats,
                       const float* __restrict__ feats, u16* __restrict__ featsBf,
                       const float* __restrict__ W, u16* __restrict__ Wt) {
  int i = blockIdx.x * 256 + threadIdx.x;
  if (i < KPAD * NV / 4) ((int4*)inv)[i] = make_int4(-1, -1, -1, -1);
  if (i < NV * 64 / 4) {
    float4 v = ((const float4*)feats)[i];
    ushort4 o;
    o.x = f2bf(v.x); o.y = f2bf(v.y); o.z = f2bf(v.z); o.w = f2bf(v.w);
    ((ushort4*)featsBf)[i] = o;
  }
  if (i < KOFF * 64 * 64) {
    int k = i >> 12, rem = i & 4095, c = rem >> 6, o = rem & 63;
    Wt[(k << 12) + (o << 6) + c] = f2bf(W[i]);
  } else if (i < 28 * 64 * 64) {
    Wt[i] = 0;                                // pad tile 27 = zeros
  }
  if (blockIdx.x == 0) stats[threadIdx.x] = 0.0f;
}

// ---- counts: mask[k] is a 1s-prefix; binary search its length ----
__global__ void k_cnt(const float* __restrict__ mask, int* __restrict__ cnt) {
  int k = threadIdx.x;
  if (k >= KOFF) return;
  int lo = 0, hi = NV;
  while (lo < hi) {
    int mid = (lo + hi) >> 1;
    if (mask[k * NV + mid] != 0.0f) lo = mid + 1; else hi = mid;
  }
  cnt[k] = lo;
}

// ---- build inverse map over valid prefix only: inv[k][out_idx] = in_idx ----
__global__ void k_build(const int* __restrict__ in_idx, const int* __restrict__ out_idx,
                        const int* __restrict__ cnt, int* __restrict__ inv) {
  int k = blockIdx.x % KOFF;
  int chunk = blockIdx.x / KOFF;              // 64 chunks per k
  int n = cnt[k];
  for (int i = chunk * 256 + threadIdx.x; i < n; i += 64 * 256)
    inv[k * NV + out_idx[k * NV + i]] = in_idx[k * NV + i];
}

// ---- main: zero-LDS, wave-independent 64-row tiles, register ping-pong pipeline ----
__global__ void __launch_bounds__(256, 2)
k_main(const u16* __restrict__ feats, const int* __restrict__ inv,
       const u16* __restrict__ Wt, float* __restrict__ out, float* __restrict__ stats) {
  const int t = threadIdx.x;
  const int lane = t & 63;
  const int w = t >> 6;
  const int qm = lane & 15;
  const int quad = lane >> 4;
  const int tile = blockIdx.x * 4 + w;
  if (tile >= NTILE) return;                  // wave-uniform; no barriers anywhere
  const int j0 = tile * NROWT;

  const short8 z8 = (short8){0, 0, 0, 0, 0, 0, 0, 0};
  int ivv[2][4];                              // ivv[k&1][mt] = src row for offset k
  short8 A0[2][4], A1[2][4], B0[2][4], B1[2][4];

  auto load_iv = [&](int k, int p) {
#pragma unroll
    for (int mt = 0; mt < 4; ++mt)
      ivv[p][mt] = inv[k * NV + j0 + mt * 16 + qm];
  };
  auto load_ops = [&](int k, int p) {         // consumes ivv[p]
    const u16* wk = Wt + (k << 12) + quad * 8;
#pragma unroll
    for (int nt = 0; nt < 4; ++nt) {
      const u16* bp = wk + ((nt * 16 + qm) << 6);
      B0[p][nt] = *(const short8*)bp;
      B1[p][nt] = *(const short8*)(bp + 32);
    }
#pragma unroll
    for (int mt = 0; mt < 4; ++mt) {
      int src = ivv[p][mt];
      A0[p][mt] = z8; A1[p][mt] = z8;
      if (src >= 0) {
        const u16* ap = feats + (long)src * 64 + quad * 8;
        A0[p][mt] = *(const short8*)ap;
        A1[p][mt] = *(const short8*)(ap + 32);
      }
    }
  };

  floatx4 acc[4][4];
#pragma unroll
  for (int mt = 0; mt < 4; ++mt)
#pragma unroll
    for (int nt = 0; nt < 4; ++nt) acc[mt][nt] = (floatx4){0.f, 0.f, 0.f, 0.f};

  // prologue: iv for k=0,1; operands for k=0
  load_iv(0, 0);
  load_iv(1, 1);
  load_ops(0, 0);

#pragma unroll 2
  for (int k = 0; k < KOFF; ++k) {
    const int p = k & 1;
    load_ops(k + 1, 1 - p);                   // prefetch next offset (pads make it safe)
    load_iv(k + 2, p);                        // iv two ahead (slices 27/28 = -1 pad)
#pragma unroll
    for (int mt = 0; mt < 4; ++mt)
#pragma unroll
      for (int nt = 0; nt < 4; ++nt) {
        acc[mt][nt] = __builtin_amdgcn_mfma_f32_16x16x32_bf16(A0[p][mt], B0[p][nt], acc[mt][nt], 0, 0, 0);
        acc[mt][nt] = __builtin_amdgcn_mfma_f32_16x16x32_bf16(A1[p][mt], B1[p][nt], acc[mt][nt], 0, 0, 0);
      }
  }

  // epilogue: pre-BN fp32 store; D layout: row = quad*4+r, col = nt*16+qm
#pragma unroll
  for (int mt = 0; mt < 4; ++mt)
#pragma unroll
    for (int nt = 0; nt < 4; ++nt)
#pragma unroll
      for (int r = 0; r < 4; ++r) {
        int orow = j0 + mt * 16 + quad * 4 + r;
        out[(long)orow * 64 + nt * 16 + qm] = acc[mt][nt][r];
      }

  // channel stats: quad-axis shfl reduce, then one atomic per (col, wave)
#pragma unroll
  for (int nt = 0; nt < 4; ++nt) {
    float s = 0.f, q = 0.f;
#pragma unroll
    for (int mt = 0; mt < 4; ++mt)
#pragma unroll
      for (int r = 0; r < 4; ++r) {
        float v = acc[mt][nt][r];
        s += v; q += v * v;
      }
    s += __shfl_xor(s, 16, 64); s += __shfl_xor(s, 32, 64);
    q += __shfl_xor(q, 16, 64); q += __shfl_xor(q, 32, 64);
    if (quad == 0) {
      atomicAdd(&stats[nt * 16 + qm], s);
      atomicAdd(&stats[64 + nt * 16 + qm], q);
    }
  }
}

// ---- apply BN + ReLU in place (finalize folded in) ----
__global__ void k_apply(float* __restrict__ out, const float* __restrict__ stats,
                        const float* __restrict__ gamma, const float* __restrict__ beta) {
  int i = blockIdx.x * 256 + threadIdx.x;
  if (i >= NV * 64 / 4) return;
  int c0 = (i & 15) * 4;
  float4 v = ((const float4*)out)[i];
  float* pv = (float*)&v;
  const float inv_n = 1.0f / (float)NV;
#pragma unroll
  for (int j = 0; j < 4; ++j) {
    int c = c0 + j;
    float mean = stats[c] * inv_n;
    float var = stats[64 + c] * inv_n - mean * mean;
    float sc = gamma[c] * rsqrtf(var + EPS_BN);
    float y = (pv[j] - mean) * sc + beta[c];
    pv[j] = y > 0.f ? y : 0.f;
  }
  ((float4*)out)[i] = v;
}

extern "C" void kernel_launch(void* const* d_in, const int* in_sizes, int n_in,
                              void* d_out, int out_size, void* d_ws, size_t ws_size,
                              hipStream_t stream) {
  const float* feats = (const float*)d_in[0];
  const float* W     = (const float*)d_in[1];
  const float* gamma = (const float*)d_in[2];
  const float* beta  = (const float*)d_in[3];
  const float* mask  = (const float*)d_in[4];
  const int* in_idx  = (const int*)d_in[5];
  const int* out_idx = (const int*)d_in[6];
  float* out = (float*)d_out;

  char* ws = (char*)d_ws;
  int* inv = (int*)ws;                        // 46.4 MB, [k][j], 29 slices
  u16* featsBf = (u16*)(ws + FEATSBF_OFF);    // 51.2 MB
  u16* Wt = (u16*)(ws + WT_OFF);              // 28 x 8 KB, [k][o][c]
  float* stats = (float*)(ws + STATS_OFF);    // 128 floats used
  int* cnt = (int*)(ws + CNT_OFF);            // 27 ints

  k_prep<<<NV * 64 / 4 / 256, 256, 0, stream>>>(inv, stats, feats, featsBf, W, Wt);
  k_cnt<<<1, 32, 0, stream>>>(mask, cnt);
  k_build<<<KOFF * 64, 256, 0, stream>>>(in_idx, out_idx, cnt, inv);
  k_main<<<(NTILE + 3) / 4, 256, 0, stream>>>(featsBf, inv, Wt, out, stats);
  k_apply<<<NV * 64 / 4 / 256, 256, 0, stream>>>(out, stats, gamma, beta);
}